// Round 1
// baseline (2235.870 us; speedup 1.0000x reference)
//
#include <hip/hip_runtime.h>
#include <hip/hip_bf16.h>

// LSTMReg: 2-layer LSTM (B=512, T=1024, F=H=64) + last-step FC(64->1).
// Round 1: fp32-vector scaffold. Layer kernel: NB=2 chains/block, 8 waves,
// weights transposed in LDS (conflict-free b128 reads), 8-way K-split with
// LDS reduction, gates on 128 threads, c-state in registers, prefetched
// next-step input. Layer0 writes h1 to d_ws; layer1 fuses the final FC.

constexpr int B_TOT = 512;
constexpr int T_LEN = 1024;
constexpr int H_DIM = 64;
constexpr int G4    = 4 * H_DIM;     // 256 gate rows
constexpr int K_DIM = 2 * H_DIM;     // 128 = [x ; h]
constexpr int NB    = 2;             // chains per block
constexpr int NTHR  = 512;           // 8 waves
constexpr int NWAVE = NTHR / 64;     // 8
constexpr int KW    = K_DIM / NWAVE; // 16 k's per wave

__device__ __forceinline__ float loadv(const float* p) { return *p; }
__device__ __forceinline__ float loadv(const __hip_bfloat16* p) { return __bfloat162float(*p); }
__device__ __forceinline__ void storev(float* p, float v) { *p = v; }
__device__ __forceinline__ void storev(__hip_bfloat16* p, float v) { *p = __float2bfloat16(v); }

__device__ __forceinline__ float sigm(float x) { return 1.0f / (1.0f + __expf(-x)); }
__device__ __forceinline__ float tanhfast(float x) { return 1.0f - 2.0f / (1.0f + __expf(2.0f * x)); }

template <typename IN_T, typename H1_T, bool IS_L1>
__global__ __launch_bounds__(NTHR, 1) void lstm_layer(
    const IN_T* __restrict__ in_seq,   // [nb_chunk, T, 64] (chunk-local)
    H1_T* __restrict__ h1_out,         // [nb_chunk, T, 64] (layer0 only)
    const float* __restrict__ w_ih,    // [256, 64]
    const float* __restrict__ w_hh,    // [256, 64]
    const float* __restrict__ b_ih,
    const float* __restrict__ b_hh,
    const float* __restrict__ fc_w,    // [64]   (layer1 only)
    const float* __restrict__ fc_b,    // [1]    (layer1 only)
    float* __restrict__ out,           // [B]    (layer1 only)
    int out_base)                      // global batch base of this chunk
{
  __shared__ float WT[K_DIM][G4];          // 128 KiB, WT[k][o] = Wcat[o][k]
  __shared__ float xh[K_DIM][NB];          // [x_t ; h] as [k][b]
  __shared__ float zred[NWAVE][NB][G4];    // 16 KiB partial sums
  __shared__ float biass[G4];
  __shared__ float fcw_s[H_DIM];
  __shared__ float hlast[NB][H_DIM];

  const int tid = threadIdx.x;
  const int b0  = blockIdx.x * NB;         // chunk-local batch base

  // Stage weights transposed into LDS (coalesced global reads).
  for (int idx = tid; idx < G4 * H_DIM; idx += NTHR) {
    int o = idx >> 6, k = idx & 63;
    WT[k][o]         = w_ih[idx];
    WT[k + H_DIM][o] = w_hh[idx];
  }
  for (int idx = tid; idx < G4; idx += NTHR) biass[idx] = b_ih[idx] + b_hh[idx];
  if (IS_L1 && tid < H_DIM) fcw_s[tid] = fc_w[tid];
  // zero h rows of xh
  for (int idx = tid; idx < H_DIM * NB; idx += NTHR)
    xh[H_DIM + (idx >> 1)][idx & 1] = 0.0f;

  const int wv = tid >> 6;     // wave id -> k-slice
  const int ln = tid & 63;
  const int o4 = ln << 2;      // 4 gate-rows per lane via b128
  const int k0 = wv * KW;

  const int gh = tid & 63;     // gate thread: h index
  const int gb = tid >> 6;     // gate thread: batch (valid for tid<128)
  float c_state = 0.0f;

  // Prefetch t=0 input.
  float xv = 0.0f;
  if (tid < H_DIM * NB) {
    int b = tid >> 6, f = tid & 63;
    xv = loadv(&in_seq[((size_t)(b0 + b) * T_LEN + 0) * H_DIM + f]);
  }

  for (int t = 0; t < T_LEN; ++t) {
    // phase 0: commit staged input row into xh
    if (tid < H_DIM * NB) xh[tid & 63][tid >> 6] = xv;
    __syncthreads();

    // issue next-step input load early (latency hidden under GEMM+gates)
    if (t + 1 < T_LEN && tid < H_DIM * NB) {
      int b = tid >> 6, f = tid & 63;
      xv = loadv(&in_seq[((size_t)(b0 + b) * T_LEN + (t + 1)) * H_DIM + f]);
    }

    // phase 1: z partials, wave wv covers k in [k0, k0+KW)
    float a00 = 0, a01 = 0, a02 = 0, a03 = 0;
    float a10 = 0, a11 = 0, a12 = 0, a13 = 0;
#pragma unroll
    for (int kk = 0; kk < KW; ++kk) {
      int k = k0 + kk;
      const float4 w4 = *reinterpret_cast<const float4*>(&WT[k][o4]);  // ds_read_b128
      const float2 xx = *reinterpret_cast<const float2*>(&xh[k][0]);   // ds_read_b64 broadcast
      a00 = __builtin_fmaf(w4.x, xx.x, a00);
      a01 = __builtin_fmaf(w4.y, xx.x, a01);
      a02 = __builtin_fmaf(w4.z, xx.x, a02);
      a03 = __builtin_fmaf(w4.w, xx.x, a03);
      a10 = __builtin_fmaf(w4.x, xx.y, a10);
      a11 = __builtin_fmaf(w4.y, xx.y, a11);
      a12 = __builtin_fmaf(w4.z, xx.y, a12);
      a13 = __builtin_fmaf(w4.w, xx.y, a13);
    }
    *reinterpret_cast<float4*>(&zred[wv][0][o4]) = make_float4(a00, a01, a02, a03);
    *reinterpret_cast<float4*>(&zred[wv][1][o4]) = make_float4(a10, a11, a12, a13);
    __syncthreads();

    // phase 2: reduce partials + gate math (torch order i,f,g,o)
    if (tid < H_DIM * NB) {
      float zi = biass[gh];
      float zf = biass[H_DIM + gh];
      float zg = biass[2 * H_DIM + gh];
      float zo = biass[3 * H_DIM + gh];
#pragma unroll
      for (int w = 0; w < NWAVE; ++w) {
        zi += zred[w][gb][gh];
        zf += zred[w][gb][H_DIM + gh];
        zg += zred[w][gb][2 * H_DIM + gh];
        zo += zred[w][gb][3 * H_DIM + gh];
      }
      float ig = sigm(zi), fg = sigm(zf), gg = tanhfast(zg), og = sigm(zo);
      c_state = fg * c_state + ig * gg;
      float hv = og * tanhfast(c_state);
      xh[H_DIM + gh][gb] = hv;  // feed next step (disjoint from phase-0 rows)
      if (!IS_L1) storev(&h1_out[((size_t)(b0 + gb) * T_LEN + t) * H_DIM + gh], hv);
      if (IS_L1 && t == T_LEN - 1) hlast[gb][gh] = hv;
    }
    // no barrier needed here: next phase-0 writes rows [0,64) (disjoint),
    // and the post-phase-0 barrier orders phase-2 writes vs next phase-1 reads.
  }

  if (IS_L1) {
    __syncthreads();
    if (tid < NB) {
      float acc = fc_b[0];
#pragma unroll
      for (int h = 0; h < H_DIM; ++h) acc += fcw_s[h] * hlast[tid][h];
      out[out_base + b0 + tid] = acc;
    }
  }
}

extern "C" void kernel_launch(void* const* d_in, const int* in_sizes, int n_in,
                              void* d_out, int out_size, void* d_ws, size_t ws_size,
                              hipStream_t stream) {
  const float* x     = (const float*)d_in[0];
  const float* w_ih0 = (const float*)d_in[1];
  const float* w_hh0 = (const float*)d_in[2];
  const float* b_ih0 = (const float*)d_in[3];
  const float* b_hh0 = (const float*)d_in[4];
  const float* w_ih1 = (const float*)d_in[5];
  const float* w_hh1 = (const float*)d_in[6];
  const float* b_ih1 = (const float*)d_in[7];
  const float* b_hh1 = (const float*)d_in[8];
  const float* fc_w  = (const float*)d_in[9];
  const float* fc_b  = (const float*)d_in[10];
  float* out = (float*)d_out;

  const size_t per_chain_f32  = (size_t)T_LEN * H_DIM * sizeof(float);
  const size_t per_chain_bf16 = (size_t)T_LEN * H_DIM * sizeof(__hip_bfloat16);

  if (ws_size >= (size_t)B_TOT * per_chain_f32) {
    // fp32 h1 in workspace (128 MiB)
    float* h1 = (float*)d_ws;
    hipLaunchKernelGGL((lstm_layer<float, float, false>), dim3(B_TOT / NB), dim3(NTHR), 0, stream,
                       x, h1, w_ih0, w_hh0, b_ih0, b_hh0,
                       (const float*)nullptr, (const float*)nullptr, (float*)nullptr, 0);
    hipLaunchKernelGGL((lstm_layer<float, float, true>), dim3(B_TOT / NB), dim3(NTHR), 0, stream,
                       h1, (float*)nullptr, w_ih1, w_hh1, b_ih1, b_hh1,
                       fc_w, fc_b, out, 0);
  } else if (ws_size >= (size_t)B_TOT * per_chain_bf16) {
    // bf16 h1 in workspace (64 MiB)
    __hip_bfloat16* h1 = (__hip_bfloat16*)d_ws;
    hipLaunchKernelGGL((lstm_layer<float, __hip_bfloat16, false>), dim3(B_TOT / NB), dim3(NTHR), 0, stream,
                       x, h1, w_ih0, w_hh0, b_ih0, b_hh0,
                       (const float*)nullptr, (const float*)nullptr, (float*)nullptr, 0);
    hipLaunchKernelGGL((lstm_layer<__hip_bfloat16, float, true>), dim3(B_TOT / NB), dim3(NTHR), 0, stream,
                       h1, (float*)nullptr, w_ih1, w_hh1, b_ih1, b_hh1,
                       fc_w, fc_b, out, 0);
  } else {
    // chunked-batch fallback, bf16 h1
    long long bc_ll = (long long)(ws_size / per_chain_bf16);
    int bc = (int)(bc_ll > B_TOT ? B_TOT : bc_ll);
    bc &= ~(NB - 1);
    if (bc < NB) bc = NB;  // last resort; ws assumed at least this big
    __hip_bfloat16* h1 = (__hip_bfloat16*)d_ws;
    for (int off = 0; off < B_TOT; off += bc) {
      int nb = (B_TOT - off < bc) ? (B_TOT - off) : bc;
      const float* xs = x + (size_t)off * T_LEN * H_DIM;
      hipLaunchKernelGGL((lstm_layer<float, __hip_bfloat16, false>), dim3(nb / NB), dim3(NTHR), 0, stream,
                         xs, h1, w_ih0, w_hh0, b_ih0, b_hh0,
                         (const float*)nullptr, (const float*)nullptr, (float*)nullptr, 0);
      hipLaunchKernelGGL((lstm_layer<__hip_bfloat16, float, true>), dim3(nb / NB), dim3(NTHR), 0, stream,
                         h1, (float*)nullptr, w_ih1, w_hh1, b_ih1, b_hh1,
                         fc_w, fc_b, out, off);
    }
  }
}